// Round 2
// baseline (212.828 us; speedup 1.0000x reference)
//
#include <hip/hip_runtime.h>
#include <hip/hip_bf16.h>

typedef __attribute__((ext_vector_type(4))) float f32x4;
typedef __attribute__((ext_vector_type(8))) short bf16x8;

// global -> LDS direct DMA, 16 B/lane. LDS dest = wave-uniform base + lane*16.
#define GLDS16(gp, lp) __builtin_amdgcn_global_load_lds( \
    (__attribute__((address_space(1))) void*)(void*)(gp), \
    (__attribute__((address_space(3))) void*)(lp), 16, 0, 0)

static constexpr int Mtot = 49152;   // 4*24*512 rows (b,h,n)
static constexpr int Otot = 512;
static constexpr int Hh   = 24;
// K order (FEATURE-major): k = f*128 + i.  f: 0=silu, 1..5=rbf(g=f-1).
// i: 0..119 = x channels, 120..127 = t_emb.  12 K-iters of BK=64
// (8 chunks of 8 k).  Chunk-major LDS [chunk][row]x16B: both ds_write_b128
// (2-way) and ds_read_b128 (structural 8-cyc min) are conflict-free.

__device__ inline unsigned short f2bf(float f) {
    __hip_bfloat16 h = __float2bfloat16(f);
    unsigned short u;
    __builtin_memcpy(&u, &h, 2);
    return u;
}

// 8 values of one feature type -> 4 packed bf16x2 words (one 16B LDS chunk).
// silu/cg are wave-uniform (runtime branch is scalar).
__device__ inline uint4 gen8(const bool silu, const float cg,
                             const float4 a, const float4 b) {
    float v[8] = {a.x, a.y, a.z, a.w, b.x, b.y, b.z, b.w};
    unsigned short s[8];
    if (silu) {
        #pragma unroll
        for (int e = 0; e < 8; ++e)
            s[e] = f2bf(v[e] * __builtin_amdgcn_rcpf(1.0f + __expf(-v[e])));
    } else {
        #pragma unroll
        for (int e = 0; e < 8; ++e) {
            const float d = 2.0f * (v[e] - cg);           // inv_h = 2
            s[e] = f2bf(__expf(-d * d));
        }
    }
    uint4 u;
    u.x = s[0] | ((unsigned)s[1] << 16);
    u.y = s[2] | ((unsigned)s[3] << 16);
    u.z = s[4] | ((unsigned)s[5] << 16);
    u.w = s[6] | ((unsigned)s[7] << 16);
    return u;
}

// Wt image: linear k-major, [C=0..95][col=0..511] x 16B;
// the 16B at (C,col) holds bf16 W[k = C*8+e][col], e = 0..7.
__global__ __launch_bounds__(256) void prep_W(
        const float* __restrict__ bw, const float* __restrict__ sw,
        uint4* __restrict__ Wt)
{
    const int tid = blockIdx.x * 256 + threadIdx.x;   // = C*512 + col; 49152 total
    const int col = tid & 511;
    const int C   = tid >> 9;
    const int f   = C >> 4;
    const int i0  = (C & 15) * 8;
    unsigned short s[8];
    if (f == 0) {
        const float4 a = *(const float4*)(bw + col * 128 + i0);
        const float4 b = *(const float4*)(bw + col * 128 + i0 + 4);
        const float v[8] = {a.x, a.y, a.z, a.w, b.x, b.y, b.z, b.w};
        #pragma unroll
        for (int e = 0; e < 8; ++e) s[e] = f2bf(v[e]);
    } else {
        #pragma unroll
        for (int e = 0; e < 8; ++e)
            s[e] = f2bf(sw[(col * 128 + i0 + e) * 5 + (f - 1)]);
    }
    uint4 u;
    u.x = s[0] | ((unsigned)s[1] << 16);
    u.y = s[2] | ((unsigned)s[3] << 16);
    u.z = s[4] | ((unsigned)s[5] << 16);
    u.w = s[6] | ((unsigned)s[7] << 16);
    Wt[tid] = u;
}

// Fused KAN GEMM: block = 128 rows x 256 cols (R=2 feature redundancy),
// 256 threads, 4 waves 2x2, wave tile 64x128, acc[4][8] (128 AGPR).
// LDS 80 KB -> 2 blocks/CU (barrier overlap across blocks, the thing that
// made the 81 us baseline work). Grid 768 = 3 clean rounds of 256 CUs.
// B double-buffered; GLDS(it+1) issued after the A barrier so it flies
// under the whole MFMA phase before the vmcnt(0) drain.
__global__ __launch_bounds__(256, 2) void gemm_kan(
        const float* __restrict__ x, const int* __restrict__ t_idx,
        const float* __restrict__ temb,
        const char* __restrict__ Wt,
        const float* __restrict__ bias,
        float* __restrict__ out)
{
    __shared__ char Alds[8 * 128 * 16];        // 16 KB, single buffer
    __shared__ char Blds[2][8 * 256 * 16];     // 2 x 32 KB double buffer

    const int t    = threadIdx.x;
    const int wave = t >> 6;
    const int lane = t & 63;
    const int ll   = lane & 15;
    const int q4   = lane >> 4;
    const int wm   = (wave >> 1) * 64;         // 0 / 64
    const int wn   = (wave & 1) * 128;         // 0 / 128

    // bijective XCD-chunked swizzle: 768 = 8 * 96; consecutive work on one
    // XCD shares x-rows (n-pairs adjacent) and keeps Wt slice L2-hot.
    const int bid  = blockIdx.x;
    const int swz  = (bid & 7) * 96 + (bid >> 3);
    const int m_base = (swz >> 1) * 128;
    const int n_base = (swz & 1) * 256;

    // ---- A-gen mapping: thread = (row, half-of-chunks) ----
    const int row = t >> 1;                    // 0..127
    const int hh  = t & 1;                     // chunks hh*4 .. hh*4+3
    const int ht  = t_idx[(m_base >> 9) % Hh];
    const float* xrow = x + (size_t)(m_base + row) * 120;
    const float* trow = temb + ht * 8;

    f32x4 acc[4][8] = {};

    // B staging: wave w stages chunks 2w, 2w+1 (4 KB each = 4 GLDS).
    auto stageB = [&](int it, int buf) {
        #pragma unroll
        for (int q = 0; q < 8; ++q) {
            const int c = 2 * wave + (q >> 2);
            const char* src = Wt + (((size_t)(it * 8 + c) * 512 + n_base) << 4)
                              + (q & 3) * 1024 + lane * 16;
            GLDS16(src, Blds[buf] + c * 4096 + (q & 3) * 1024);
        }
    };

    auto chanptr = [&](int c0) -> const float* {
        return (c0 < 120) ? (xrow + c0) : (trow + (c0 - 120));
    };

    // prime x pipeline (iter 0, chunk j=0: channels hh*32..hh*32+7)
    float4 pa, pb;
    {
        const float* p = chanptr(hh * 32);
        pa = *(const float4*)p;
        pb = *(const float4*)(p + 4);
    }

    stageB(0, 0);

    #pragma unroll 2
    for (int it = 0; it < 12; ++it) {
        const int  half = it & 1;              // compile-time under unroll 2
        const bool silu = (it < 2);
        const float cg  = -1.0f + 0.5f * (float)((it >> 1) - 1);

        // ---- generate A(it): 4 chunks/thread, x pipelined one chunk ahead
        #pragma unroll
        for (int j = 0; j < 4; ++j) {
            const float4 fa = pa, fb = pb;
            // prefetch x for next chunk (chunk0 of next iter when j==3)
            const int jn = (j + 1) & 3;
            const int hn = (j == 3) ? (half ^ 1) : half;
            const float* p = chanptr(hn * 64 + hh * 32 + jn * 8);
            pa = *(const float4*)p;
            pb = *(const float4*)(p + 4);
            const uint4 u = gen8(silu, cg, fa, fb);
            *(uint4*)(Alds + (((hh * 4 + j) * 128 + row) << 4)) = u;
        }
        __syncthreads();                       // A(it) visible to all waves

        if (it + 1 < 12) stageB(it + 1, (it + 1) & 1);   // hides under MFMA

        // ---- MFMA(it): A in Alds, B in Blds[it&1] ----
        const char* B = Blds[it & 1];
        #pragma unroll
        for (int kk = 0; kk < 2; ++kk) {
            const int ch = kk * 4 + q4;                  // chunk 0..7
            bf16x8 af[4], bf[8];
            #pragma unroll
            for (int mi = 0; mi < 4; ++mi)
                af[mi] = *(const bf16x8*)(Alds + ((ch * 128 + wm + mi * 16 + ll) << 4));
            #pragma unroll
            for (int ni = 0; ni < 8; ++ni)
                bf[ni] = *(const bf16x8*)(B + ((ch * 256 + wn + ni * 16 + ll) << 4));
            #pragma unroll
            for (int mi = 0; mi < 4; ++mi)
                #pragma unroll
                for (int ni = 0; ni < 8; ++ni)
                    acc[mi][ni] = __builtin_amdgcn_mfma_f32_16x16x32_bf16(
                        af[mi], bf[ni], acc[mi][ni], 0, 0, 0);
        }
        __syncthreads();     // A consumed (safe to rewrite) + GLDS(it+1) drained
    }

    // C/D layout: col = lane&15, row = (lane>>4)*4 + reg  [m89-verified]
    const int col0 = n_base + wn + ll;
    const int row0 = m_base + wm + q4 * 4;
    #pragma unroll
    for (int ni = 0; ni < 8; ++ni) {
        const int col = col0 + ni * 16;
        const float bv = bias[col];
        #pragma unroll
        for (int mi = 0; mi < 4; ++mi) {
            #pragma unroll
            for (int r = 0; r < 4; ++r) {
                out[(size_t)(row0 + mi * 16 + r) * Otot + col] = acc[mi][ni][r] + bv;
            }
        }
    }
}

extern "C" void kernel_launch(void* const* d_in, const int* in_sizes, int n_in,
                              void* d_out, int out_size, void* d_ws, size_t ws_size,
                              hipStream_t stream) {
    const float* x    = (const float*)d_in[0];
    const int*   tidx = (const int*)  d_in[1];
    const float* temb = (const float*)d_in[2];
    const float* bw   = (const float*)d_in[3];
    const float* bb   = (const float*)d_in[4];
    const float* sw   = (const float*)d_in[5];
    float* out = (float*)d_out;

    char* Wt = (char*)d_ws;   // 96*512*16 = 768 KiB linear k-major image

    prep_W<<<49152 / 256, 256, 0, stream>>>(bw, sw, (uint4*)Wt);
    gemm_kan<<<768, 256, 0, stream>>>(x, tidx, temb, Wt, bb, out);
}

// Round 3
// 171.136 us; speedup vs baseline: 1.2436x; 1.2436x over previous
//
#include <hip/hip_runtime.h>
#include <hip/hip_bf16.h>

typedef __attribute__((ext_vector_type(4))) float f32x4;
typedef __attribute__((ext_vector_type(8))) short bf16x8;

// global -> LDS direct DMA, 16 B/lane. LDS dest = wave-uniform base + lane*16.
#define GLDS16(gp, lp) __builtin_amdgcn_global_load_lds( \
    (__attribute__((address_space(1))) void*)(void*)(gp), \
    (__attribute__((address_space(3))) void*)(lp), 16, 0, 0)

static constexpr int Mtot = 49152;   // 4*24*512 rows (b,h,n)
static constexpr int Otot = 512;
static constexpr int Hh   = 24;
// K order: k = i*6 + f (i: 0..119 = x-ch, 120..127 = t_emb; f: silu, rbf0..4)
// 8 K-iters of BK=96 (16 channels). LDS rows padded to 256B, chunk swizzle
// phys = ck ^ (row&7) baked into both A (ds_write) and B (prep_W image).
// ROUND-0 STRUCTURE, narrowed: block = 64 rows x 256 cols, 4 waves 1x4,
// wave tile 64x64 (acc[4][4] = 64 AGPR -- the proven register envelope).
// Feature redundancy drops 4x -> 2x; RBF math uses the u=exp(4v) algebra.

__device__ inline unsigned short f2bf(float f) {
    __hip_bfloat16 h = __float2bfloat16(f);
    unsigned short u;
    __builtin_memcpy(&u, &h, 2);
    return u;
}

// Wt image: [iter(8)][o(512)][16 chunks x 16B]; chunk p holds logical chunk
// ck = p ^ (o&7) (zeros if ck>=12). Logical: k_local = ck*8+e, k = iter*96+k_local.
// (identical to the verified round-0 image)
__global__ __launch_bounds__(256) void prep_W(
        const float* __restrict__ bw, const float* __restrict__ sw,
        uint4* __restrict__ Wt)
{
    int tid = blockIdx.x * 256 + threadIdx.x;   // (iter*512 + o)*16 + p ; 65536 total
    int p    = tid & 15;
    int o    = (tid >> 4) & 511;
    int iter = tid >> 13;
    int ck = p ^ (o & 7);
    unsigned u[4] = {0u, 0u, 0u, 0u};
    if (ck < 12) {
        unsigned short s[8];
        #pragma unroll
        for (int e = 0; e < 8; ++e) {
            int k = iter * 96 + ck * 8 + e;
            int i = k / 6, f = k - i * 6;
            float v = (f == 0) ? bw[o * 128 + i] : sw[(o * 128 + i) * 5 + (f - 1)];
            s[e] = f2bf(v);
        }
        #pragma unroll
        for (int n = 0; n < 4; ++n) u[n] = s[2 * n] | ((unsigned)s[2 * n + 1] << 16);
    }
    Wt[tid] = make_uint4(u[0], u[1], u[2], u[3]);
}

__global__ __launch_bounds__(256, 2) void gemm_kan(
        const float* __restrict__ x, const int* __restrict__ t_idx,
        const float* __restrict__ temb,
        const char* __restrict__ Wt,
        const float* __restrict__ bias,
        float* __restrict__ out)
{
    __shared__ char AsB[64 * 256];    // 16 KB: 64 rows, 12 chunks (+4 pad), swizzled
    __shared__ char BsB[256 * 256];   // 64 KB: 256 cols, GLDS verbatim image
    const int t    = threadIdx.x;
    const int wave = t >> 6;
    const int lane = t & 63;
    const int ll   = lane & 15;
    const int q4   = lane >> 4;
    const int wn   = wave * 64;                 // 1x4 wave grid, wm = 0
    const int m_base = blockIdx.y * 64;         // y = m (768), x = n (2):
    const int n_base = blockIdx.x * 256;        // n-pair adjacent in dispatch

    f32x4 acc[4][4] = {};

    // ---- B staging: wave stages its own 64-col strip (16 KB = 16 GLDS) ----
    const char* bsrc0 = Wt + (size_t)(n_base + wn) * 256 + lane * 16;
    char* ldsB = BsB + wn * 256;      // wave-uniform; lane*16 added by HW

    // ---- A generation mapping: thread = (row, quarter of 4 channels) ----
    const int row = t >> 2;                     // 0..63
    const int q   = t & 3;                      // channels 4q..4q+3 each iter
    const int ht  = t_idx[(m_base >> 9) % Hh];  // uniform per block
    const float* xrow = x + (size_t)(m_base + row) * 120;
    const float* trow = temb + ht * 8;

    auto chanptr = [&](int i0) -> const float* {
        return (i0 < 120) ? (xrow + i0) : (trow + (i0 - 120));
    };

    float4 xv = *(const float4*)chanptr(4 * q);   // prime iter 0

    constexpr float C1 = 0.36787944117f;   // e^-1
    constexpr float C4 = 0.01831563889f;   // e^-4

    #pragma unroll
    for (int it = 0; it < 8; ++it) {
        // stage B tile (async); flies under the feature VALU below
        const char* bsrc = bsrc0 + (size_t)it * (512 * 256);
        #pragma unroll
        for (int p = 0; p < 16; ++p)
            GLDS16(bsrc + p * 1024, ldsB + p * 1024);

        const float4 cur = xv;
        if (it < 7) xv = *(const float4*)chanptr((it + 1) * 16 + 4 * q);

        // 4 channels x 6 features -> 24 bf16 (3 swizzled 16B chunks)
        float v[4] = {cur.x, cur.y, cur.z, cur.w};
        unsigned short s[24];
        #pragma unroll
        for (int c = 0; c < 4; ++c) {
            const float vv = v[c];
            // silu
            s[c * 6 + 0] = f2bf(vv * __builtin_amdgcn_rcpf(1.0f + __expf(-vv)));
            // rbf(c_g) = exp(-4(v-c_g)^2) = t * u^(2c_g) * e^(-4c_g^2),
            //   t = exp(-4v^2), u = exp(4v);  c_g in {-1,-.5,0,.5,1}
            const float tt = __expf(-4.0f * vv * vv);
            const float uu = __expf(4.0f * vv);
            const float rr = __builtin_amdgcn_rcpf(uu);
            const float tu = tt * uu, tr = tt * rr;
            s[c * 6 + 1] = f2bf(tr * rr * C4);   // c_g = -1
            s[c * 6 + 2] = f2bf(tr * C1);        // c_g = -0.5
            s[c * 6 + 3] = f2bf(tt);             // c_g = 0
            s[c * 6 + 4] = f2bf(tu * C1);        // c_g = +0.5
            s[c * 6 + 5] = f2bf(tu * uu * C4);   // c_g = +1
        }
        // write 3 swizzled 16B chunks: logical ck = 3q + j
        #pragma unroll
        for (int j = 0; j < 3; ++j) {
            const int ck = 3 * q + j;
            const int phys = ck ^ (row & 7);
            unsigned u[4];
            #pragma unroll
            for (int n = 0; n < 4; ++n)
                u[n] = s[j * 8 + 2 * n] | ((unsigned)s[j * 8 + 2 * n + 1] << 16);
            *(uint4*)(AsB + row * 256 + phys * 16) = make_uint4(u[0], u[1], u[2], u[3]);
        }
        __syncthreads();               // drain GLDS B + ds_writes A

        #pragma unroll
        for (int kk = 0; kk < 3; ++kk) {
            bf16x8 af[4], bf[4];
            #pragma unroll
            for (int mi = 0; mi < 4; ++mi) {
                const int r = mi * 16 + ll;
                af[mi] = *(const bf16x8*)(AsB + r * 256 + (((kk * 4 + q4) ^ (ll & 7)) * 16));
            }
            #pragma unroll
            for (int ni = 0; ni < 4; ++ni) {
                const int r = wn + ni * 16 + ll;
                bf[ni] = *(const bf16x8*)(BsB + r * 256 + (((kk * 4 + q4) ^ (ll & 7)) * 16));
            }
            #pragma unroll
            for (int mi = 0; mi < 4; ++mi)
                #pragma unroll
                for (int ni = 0; ni < 4; ++ni)
                    acc[mi][ni] = __builtin_amdgcn_mfma_f32_16x16x32_bf16(
                        af[mi], bf[ni], acc[mi][ni], 0, 0, 0);
        }
        __syncthreads();               // LDS consumed before next stage
    }

    // C/D layout: col = lane&15, row = (lane>>4)*4 + reg  [m89-verified]
    const int col0 = n_base + wn + ll;
    const int row0 = m_base + q4 * 4;
    #pragma unroll
    for (int ni = 0; ni < 4; ++ni) {
        const int col = col0 + ni * 16;
        const float bv = bias[col];
        #pragma unroll
        for (int mi = 0; mi < 4; ++mi) {
            #pragma unroll
            for (int r = 0; r < 4; ++r) {
                out[(long)(row0 + mi * 16 + r) * Otot + col] = acc[mi][ni][r] + bv;
            }
        }
    }
}

extern "C" void kernel_launch(void* const* d_in, const int* in_sizes, int n_in,
                              void* d_out, int out_size, void* d_ws, size_t ws_size,
                              hipStream_t stream) {
    const float* x    = (const float*)d_in[0];
    const int*   tidx = (const int*)  d_in[1];
    const float* temb = (const float*)d_in[2];
    const float* bw   = (const float*)d_in[3];
    const float* bb   = (const float*)d_in[4];
    const float* sw   = (const float*)d_in[5];
    float* out = (float*)d_out;

    char* Wt = (char*)d_ws;   // 8*512*256 B = 1 MiB swizzled image

    prep_W<<<65536 / 256, 256, 0, stream>>>(bw, sw, (uint4*)Wt);
    // x = n (2 tiles, adjacent ids share the same x rows), y = m (768)
    gemm_kan<<<dim3(Otot / 256, Mtot / 64), 256, 0, stream>>>(
        x, tidx, temb, Wt, bb, out);
}

// Round 4
// 167.572 us; speedup vs baseline: 1.2701x; 1.0213x over previous
//
#include <hip/hip_runtime.h>
#include <hip/hip_bf16.h>

typedef __attribute__((ext_vector_type(4))) float f32x4;
typedef __attribute__((ext_vector_type(8))) short bf16x8;

// global -> LDS direct DMA, 16 B/lane. LDS dest = wave-uniform base + lane*16.
#define GLDS16(gp, lp) __builtin_amdgcn_global_load_lds( \
    (__attribute__((address_space(1))) void*)(void*)(gp), \
    (__attribute__((address_space(3))) void*)(lp), 16, 0, 0)

static constexpr int Mtot = 49152;   // 4*24*512 rows (b,h,n)
static constexpr int Otot = 512;
static constexpr int Hh   = 24;
// K order: k = i*6 + f (i: 0..119 = x-ch, 120..127 = t_emb; f: silu, rbf0..4)
// 8 K-iters of BK=96 = 12 chunks of 8 k.  CHUNK-MAJOR LDS [chunk][row]x16B
// for both A and B: structural-minimum bank pattern on ds_read_b128 /
// ds_write_b128, no pad, no XOR.  A=24KB + B=24KB = 48KB -> 3 blocks/CU.

__device__ inline unsigned short f2bf(float f) {
    __hip_bfloat16 h = __float2bfloat16(f);
    unsigned short u;
    __builtin_memcpy(&u, &h, 2);
    return u;
}

// Wt image: [iter(8)][ck(12)][col(512)] x 16B.
// The 16B at (cc = iter*12+ck, col) holds bf16 W[k = cc*8 + e][col], e=0..7.
__global__ __launch_bounds__(256) void prep_W(
        const float* __restrict__ bw, const float* __restrict__ sw,
        uint4* __restrict__ Wt)
{
    const int tid = blockIdx.x * 256 + threadIdx.x;  // cc*512 + col; 49152 total
    const int col = tid & 511;
    const int cc  = tid >> 9;          // iter*12 + ck, 0..95
    const int k0  = cc * 8;            // global k of element 0
    unsigned short s[8];
    #pragma unroll
    for (int e = 0; e < 8; ++e) {
        const int k = k0 + e;
        const int i = k / 6, f = k - i * 6;
        const float v = (f == 0) ? bw[col * 128 + i]
                                 : sw[(col * 128 + i) * 5 + (f - 1)];
        s[e] = f2bf(v);
    }
    uint4 u;
    u.x = s[0] | ((unsigned)s[1] << 16);
    u.y = s[2] | ((unsigned)s[3] << 16);
    u.z = s[4] | ((unsigned)s[5] << 16);
    u.w = s[6] | ((unsigned)s[7] << 16);
    Wt[tid] = u;
}

// Fused KAN GEMM: round-0 geometry (block 128x128, 4 waves 2x2, wave 64x64,
// acc[4][4]) + chunk-major 48KB LDS (3 blocks/CU) + cheap 2-exp RBF algebra.
__global__ __launch_bounds__(256, 3) void gemm_kan(
        const float* __restrict__ x, const int* __restrict__ t_idx,
        const float* __restrict__ temb,
        const char* __restrict__ Wt,
        const float* __restrict__ bias,
        float* __restrict__ out)
{
    __shared__ char Alds[12 * 128 * 16];   // 24 KB, [chunk][row]x16B
    __shared__ char Blds[12 * 128 * 16];   // 24 KB, [chunk][col]x16B
    const int t    = threadIdx.x;
    const int wave = t >> 6;
    const int lane = t & 63;
    const int ll   = lane & 15;
    const int q4   = lane >> 4;
    const int wm   = (wave >> 1) * 64;
    const int wn   = (wave & 1) * 64;

    // bijective XCD swizzle: 1536 = 8*192; one XCD gets contiguous swz range,
    // so the 4 n-blocks sharing an x-panel sit on the same XCD (L2 reuse).
    const int bid = blockIdx.x;
    const int swz = (bid & 7) * 192 + (bid >> 3);
    const int m_base = (swz >> 2) * 128;
    const int n_base = (swz & 3) * 128;

    // ---- A generation mapping: thread = (row, half of 16 channels) ----
    const int row = t >> 1;                     // 0..127
    const int hh  = t & 1;                      // channels hh*8 .. hh*8+7
    const int ht  = t_idx[(m_base >> 9) % Hh];  // uniform per block
    const float* xrow = x + (size_t)(m_base + row) * 120;
    const float* trow = temb + ht * 8;

    auto chanptr = [&](int i0) -> const float* {
        return (i0 < 120) ? (xrow + i0) : (trow + (i0 - 120));
    };

    f32x4 acc[4][4] = {};

    // prime x pipeline (iter 0: channels hh*8..hh*8+7; never straddles x/temb)
    float4 xa, xb;
    {
        const float* p = chanptr(hh * 8);
        xa = *(const float4*)p;
        xb = *(const float4*)(p + 4);
    }

    constexpr float C1 = 0.36787944117f;   // e^-1
    constexpr float C4 = 0.01831563889f;   // e^-4

    #pragma unroll
    for (int it = 0; it < 8; ++it) {
        // ---- stage B(it): wave stages chunks 3w..3w+2, 2 GLDS each (1 KB) ----
        #pragma unroll
        for (int j = 0; j < 6; ++j) {
            const int c = wave * 3 + (j >> 1);
            const int g = (j & 1) * 64;
            const char* src = Wt + (((size_t)(it * 12 + c) * 512 + n_base + g) << 4)
                              + lane * 16;
            GLDS16(src, Blds + ((c * 128 + g) << 4));
        }

        const float4 ca = xa, cb = xb;
        if (it < 7) {
            const float* p = chanptr((it + 1) * 16 + hh * 8);
            xa = *(const float4*)p;
            xb = *(const float4*)(p + 4);
        }

        // ---- 8 channels x 6 features -> 48 bf16 (6 chunks) ----
        const float v[8] = {ca.x, ca.y, ca.z, ca.w, cb.x, cb.y, cb.z, cb.w};
        unsigned short s[48];
        #pragma unroll
        for (int c = 0; c < 8; ++c) {
            const float vv = v[c];
            // silu
            s[c * 6 + 0] = f2bf(vv * __builtin_amdgcn_rcpf(1.0f + __expf(-vv)));
            // rbf(c_g) = exp(-4(v-c_g)^2) = t * u^(2c_g) * e^(-4c_g^2),
            //   t = exp(-4v^2), u = exp(4v);  c_g in {-1,-.5,0,.5,1}
            const float tt = __expf(-4.0f * vv * vv);
            const float uu = __expf(4.0f * vv);
            const float rr = __builtin_amdgcn_rcpf(uu);
            const float tu = tt * uu, tr = tt * rr;
            s[c * 6 + 1] = f2bf(tr * rr * C4);   // c_g = -1
            s[c * 6 + 2] = f2bf(tr * C1);        // c_g = -0.5
            s[c * 6 + 3] = f2bf(tt);             // c_g = 0
            s[c * 6 + 4] = f2bf(tu * C1);        // c_g = +0.5
            s[c * 6 + 5] = f2bf(tu * uu * C4);   // c_g = +1
        }
        // ---- write 6 chunk-major 16B slots: ck = 6*hh + j ----
        #pragma unroll
        for (int j = 0; j < 6; ++j) {
            const int ck = 6 * hh + j;
            unsigned u[4];
            #pragma unroll
            for (int n = 0; n < 4; ++n)
                u[n] = s[j * 8 + 2 * n] | ((unsigned)s[j * 8 + 2 * n + 1] << 16);
            *(uint4*)(Alds + ((ck * 128 + row) << 4)) = make_uint4(u[0], u[1], u[2], u[3]);
        }
        __syncthreads();               // drain GLDS B + ds_writes A

        #pragma unroll
        for (int kk = 0; kk < 3; ++kk) {
            const int ch = kk * 4 + q4;                  // chunk 0..11
            bf16x8 af[4], bf[4];
            #pragma unroll
            for (int mi = 0; mi < 4; ++mi)
                af[mi] = *(const bf16x8*)(Alds + ((ch * 128 + wm + mi * 16 + ll) << 4));
            #pragma unroll
            for (int ni = 0; ni < 4; ++ni)
                bf[ni] = *(const bf16x8*)(Blds + ((ch * 128 + wn + ni * 16 + ll) << 4));
            #pragma unroll
            for (int mi = 0; mi < 4; ++mi)
                #pragma unroll
                for (int ni = 0; ni < 4; ++ni)
                    acc[mi][ni] = __builtin_amdgcn_mfma_f32_16x16x32_bf16(
                        af[mi], bf[ni], acc[mi][ni], 0, 0, 0);
        }
        __syncthreads();               // LDS consumed before next stage
    }

    // C/D layout: col = lane&15, row = (lane>>4)*4 + reg  [m89-verified]
    const int col0 = n_base + wn + ll;
    const int row0 = m_base + wm + q4 * 4;
    #pragma unroll
    for (int ni = 0; ni < 4; ++ni) {
        const int col = col0 + ni * 16;
        const float bv = bias[col];
        #pragma unroll
        for (int mi = 0; mi < 4; ++mi) {
            #pragma unroll
            for (int r = 0; r < 4; ++r) {
                out[(long)(row0 + mi * 16 + r) * Otot + col] = acc[mi][ni][r] + bv;
            }
        }
    }
}

extern "C" void kernel_launch(void* const* d_in, const int* in_sizes, int n_in,
                              void* d_out, int out_size, void* d_ws, size_t ws_size,
                              hipStream_t stream) {
    const float* x    = (const float*)d_in[0];
    const int*   tidx = (const int*)  d_in[1];
    const float* temb = (const float*)d_in[2];
    const float* bw   = (const float*)d_in[3];
    const float* bb   = (const float*)d_in[4];
    const float* sw   = (const float*)d_in[5];
    float* out = (float*)d_out;

    char* Wt = (char*)d_ws;   // 8*12*512*16 = 768 KiB linear chunk-major image

    prep_W<<<49152 / 256, 256, 0, stream>>>(bw, sw, (uint4*)Wt);
    gemm_kan<<<1536, 256, 0, stream>>>(x, tidx, temb, Wt, bb, out);
}